// Round 14
// baseline (288.790 us; speedup 1.0000x reference)
//
#include <hip/hip_runtime.h>
#include <hip/hip_bf16.h>

#define T_TOK 4096
#define DDIM  1024
#define HDIM  2048
#define NEXP  8
#define MAXSLOT 9216   // 2T padded: each expert base 128-aligned

typedef __attribute__((ext_vector_type(4))) float f32x4;
typedef __attribute__((ext_vector_type(8))) short s16x8;
typedef __hip_bfloat16 bf16;

typedef const void __attribute__((address_space(1))) gvoid;
typedef void __attribute__((address_space(3))) svoid;

__device__ __forceinline__ void gload16(const void* g, void* l) {
    // async global->LDS, 16B/lane; LDS dest = wave-uniform base, HW adds lane*16
    __builtin_amdgcn_global_load_lds((gvoid*)g, (svoid*)l, 16, 0, 0);
}

// Swizzled LDS layout for [R rows][32 k] bf16 tiles packed as (R/2) ldsrows x 64
// elems (read + staging maps correctness-proven R10-R13): row rr -> ldsrow rr>>1;
// chunk ch = 4*(rr&1) + kq/8 stored at slot ch ^ (ldsrow&7).  0 bank conflicts.
__device__ __forceinline__ int frag_off(int rr, int kq) {
    int lr = rr >> 1;
    int ch = ((rr & 1) << 2) + (kq >> 3);
    return lr * 64 + (ch ^ (lr & 7)) * 8;
}

// ---------------- router (fp64 acc, top-2 softmax) + fused x->bf16 cast ----------------
__global__ void router_cast_kernel(const float* __restrict__ x, const float* __restrict__ rw,
                                   int* __restrict__ r_e, float* __restrict__ r_w,
                                   bf16* __restrict__ xb) {
    int wave = threadIdx.x >> 6, lane = threadIdx.x & 63;
    int t = blockIdx.x * 4 + wave;
    const float* xr = x + (size_t)t * DDIM;
    bf16* xbr = xb + (size_t)t * DDIM;
    double acc[NEXP];
#pragma unroll
    for (int e = 0; e < NEXP; ++e) acc[e] = 0.0;
#pragma unroll
    for (int c = 0; c < 4; ++c) {
        int d = c * 256 + lane * 4;
        float4 v = *reinterpret_cast<const float4*>(xr + d);
        union { ushort4 u; bf16 h[4]; } o;
        o.h[0] = __float2bfloat16(v.x);
        o.h[1] = __float2bfloat16(v.y);
        o.h[2] = __float2bfloat16(v.z);
        o.h[3] = __float2bfloat16(v.w);
        *reinterpret_cast<ushort4*>(xbr + d) = o.u;
        const float* rw0 = rw + (size_t)d * NEXP;
#pragma unroll
        for (int j = 0; j < 4; ++j) {
            float xv = (&v.x)[j];
            const float* rwr = rw0 + j * NEXP;
#pragma unroll
            for (int e = 0; e < NEXP; ++e) acc[e] += (double)xv * (double)rwr[e];
        }
    }
#pragma unroll
    for (int e = 0; e < NEXP; ++e) {
#pragma unroll
        for (int off = 32; off > 0; off >>= 1) acc[e] += __shfl_down(acc[e], off);
    }
    if (lane == 0) {
        int i0 = 0; double v0 = acc[0];
#pragma unroll
        for (int e = 1; e < NEXP; ++e) if (acc[e] > v0) { v0 = acc[e]; i0 = e; }
        int i1 = -1; double v1 = -1e300;
#pragma unroll
        for (int e = 0; e < NEXP; ++e) { if (e == i0) continue; if (acc[e] > v1) { v1 = acc[e]; i1 = e; } }
        float w0 = 1.0f / (1.0f + expf((float)(v1 - v0)));
        float w1 = 1.0f - w0;
        r_e[2*t]   = i0; r_e[2*t+1] = i1;
        r_w[2*t]   = w0; r_w[2*t+1] = w1;
    }
}

// ------- fused binning: count + 128-ALIGNED scan + fill, one block -------
__global__ void binning_kernel(const int* __restrict__ r_e, const float* __restrict__ r_w,
                               int* __restrict__ offs, int* __restrict__ cnt,
                               int* __restrict__ list, float* __restrict__ slot_w) {
    __shared__ int scnt[NEXP], scur[NEXP], soff[NEXP + 1];
    int tid = threadIdx.x;
    if (tid < NEXP) { scnt[tid] = 0; scur[tid] = 0; }
    __syncthreads();
    for (int i = tid; i < 2 * T_TOK; i += 512) atomicAdd(&scnt[r_e[i]], 1);
    __syncthreads();
    if (tid == 0) {
        int s = 0;
        for (int e = 0; e < NEXP; ++e) { soff[e] = s; s += (scnt[e] + 127) & ~127; }
        soff[NEXP] = s;
    }
    __syncthreads();
    if (tid < NEXP + 1) offs[tid] = soff[tid];
    if (tid < NEXP) cnt[tid] = scnt[tid];
    for (int i = tid; i < 2 * T_TOK; i += 512) {
        int e = r_e[i];
        int pos = atomicAdd(&scur[e], 1);
        int slot = soff[e] + pos;
        list[slot] = i >> 1;
        slot_w[slot] = r_w[i];
    }
}

// -------- wg+wu transpose+cast in ONE launch: z in [0,16), which = z>>3 --------
__global__ void transpose_gu_kernel(const float* __restrict__ wg, const float* __restrict__ wu,
                                    bf16* __restrict__ wguT) {
    __shared__ bf16 tile[64][68];
    int which = blockIdx.z >> 3;            // 0 = gate, 1 = up
    int e = blockIdx.z & 7;
    const float* inp = (which ? wu : wg) + (size_t)e * DDIM * HDIM;
    bf16* outp = wguT + (size_t)e * 2 * HDIM * DDIM;
    int r0 = blockIdx.x * 64, c0 = blockIdx.y * 64;   // r over D, c over H
    int tid = threadIdx.x;
#pragma unroll
    for (int i = 0; i < 4; ++i) {
        int idx = i * 256 + tid;
        int r = idx >> 4, c4 = (idx & 15) * 4;
        float4 v = *reinterpret_cast<const float4*>(inp + (size_t)(r0 + r) * HDIM + c0 + c4);
        union { ushort4 u; bf16 h[4]; } o;
        o.h[0] = __float2bfloat16(v.x);
        o.h[1] = __float2bfloat16(v.y);
        o.h[2] = __float2bfloat16(v.z);
        o.h[3] = __float2bfloat16(v.w);
        *reinterpret_cast<ushort4*>(&tile[r][c4]) = o.u;
    }
    __syncthreads();
#pragma unroll
    for (int i = 0; i < 4; ++i) {
        int idx = i * 256 + tid;
        int c = idx >> 4, r4 = (idx & 15) * 4;
        union { ushort4 u; bf16 h[4]; } w;
        w.h[0] = tile[r4 + 0][c];
        w.h[1] = tile[r4 + 1][c];
        w.h[2] = tile[r4 + 2][c];
        w.h[3] = tile[r4 + 3][c];
        *reinterpret_cast<ushort4*>(outp + ((size_t)(c0 + c) * 2 + which) * DDIM + r0 + r4) = w.u;
    }
}

// -------- wd transpose+cast: [E][H][D] -> [E][D][H] --------
__global__ void transpose_wd_kernel(const float* __restrict__ wd, bf16* __restrict__ wdT) {
    __shared__ bf16 tile[64][68];
    const float* inp = wd + (size_t)blockIdx.z * HDIM * DDIM;
    bf16* outp = wdT + (size_t)blockIdx.z * DDIM * HDIM;
    int r0 = blockIdx.x * 64, c0 = blockIdx.y * 64;   // r over H, c over D
    int tid = threadIdx.x;
#pragma unroll
    for (int i = 0; i < 4; ++i) {
        int idx = i * 256 + tid;
        int r = idx >> 4, c4 = (idx & 15) * 4;
        float4 v = *reinterpret_cast<const float4*>(inp + (size_t)(r0 + r) * DDIM + c0 + c4);
        union { ushort4 u; bf16 h[4]; } o;
        o.h[0] = __float2bfloat16(v.x);
        o.h[1] = __float2bfloat16(v.y);
        o.h[2] = __float2bfloat16(v.z);
        o.h[3] = __float2bfloat16(v.w);
        *reinterpret_cast<ushort4*>(&tile[r][c4]) = o.u;
    }
    __syncthreads();
#pragma unroll
    for (int i = 0; i < 4; ++i) {
        int idx = i * 256 + tid;
        int c = idx >> 4, r4 = (idx & 15) * 4;
        union { ushort4 u; bf16 h[4]; } w;
        w.h[0] = tile[r4 + 0][c];
        w.h[1] = tile[r4 + 1][c];
        w.h[2] = tile[r4 + 2][c];
        w.h[3] = tile[r4 + 3][c];
        *reinterpret_cast<ushort4*>(outp + (size_t)(c0 + c) * HDIM + r0 + r4) = w.u;
    }
}

// expert lookup in padded slot space
__device__ __forceinline__ int find_expert(const int* offs, int slot0) {
    int e = 0;
#pragma unroll
    for (int i = 0; i < NEXP - 1; ++i) e += (offs[e + 1] <= slot0) ? 1 : 0;
    return e;
}

// ======== pass 1: gate+up as ONE GEMM over interleaved wguT [2H][D] ========
// 128(M) x 256(N) tile, BK=32, 8 waves (2M x 4N, wave-out 64x64). Widened N-tile
// halves A-staging traffic (the R13 finding: ~10 TB/s staging-path ceiling is
// the binder, not schedule). LDS: A 2x8KB + B 2x16KB = 48 KB. Single-barrier
// depth-2 cadence (R12-proven). 3 loads/thread/tile.
__global__ __launch_bounds__(512, 2)
void gateup_kernel(const bf16* __restrict__ xb, const bf16* __restrict__ wguT,
                   const int* __restrict__ offs, const int* __restrict__ cnt,
                   const int* __restrict__ list, bf16* __restrict__ hbuf) {
    int slot0 = blockIdx.y * 128;
    if (slot0 >= offs[NEXP]) return;
    int e = find_expert(offs, slot0);
    int base = offs[e];
    int ne = cnt[e];
    int m0 = slot0 - base;
    int n0 = blockIdx.x * 256;       // in 2H=4096 interleaved space

    __shared__ bf16 As[2][4096];     // 128 rows x 32 k (8 KB/buf), swizzled
    __shared__ bf16 Bs[2][8192];     // 256 rows x 32 k (16 KB/buf), swizzled

    int tid = threadIdx.x, lane = tid & 63, wid = tid >> 6;   // 8 waves

    const bf16* bbase = wguT + (size_t)e * (2 * HDIM) * DDIM + (size_t)n0 * DDIM;

    // staging maps (proven R10): wave-issue q writes elems q*512 + lane*8;
    // lr = q*8 + (lane>>3), slot c = lane&7 holds global chunk c^(lr&7).
    // A: 8 issues (q = wid).  B: 16 issues (q = wid, wid+8).
    const bf16* aS; const bf16* bS[2];
    int sdstA, sdstB[2];
    {
        int q = wid;
        int lr = q * 8 + (lane >> 3);          // [0,64)
        int ch = (lane & 7) ^ (lr & 7);
        int rr = 2 * lr + (ch >> 2);           // [0,128)
        int koff = (ch & 3) * 8;
        int r = m0 + rr; if (r > ne - 1) r = ne - 1;   // clamp: read-only, never stored
        aS = xb + (size_t)list[base + r] * DDIM + koff;
        sdstA = q * 512;
    }
#pragma unroll
    for (int j = 0; j < 2; ++j) {
        int q = wid + j * 8;
        int lr = q * 8 + (lane >> 3);          // [0,128)
        int ch = (lane & 7) ^ (lr & 7);
        int rr = 2 * lr + (ch >> 2);           // [0,256)
        int koff = (ch & 3) * 8;
        bS[j] = bbase + (size_t)rr * DDIM + koff;
        sdstB[j] = q * 512;
    }

    int rl = lane & 15, kq = 8 * (lane >> 4);
    int wrow = (wid >> 2) * 64;      // 2 M waves
    int wcol = (wid & 3) * 64;       // 4 N waves
    int offA[4], offB[4];
#pragma unroll
    for (int mi = 0; mi < 4; ++mi) offA[mi] = frag_off(wrow + mi * 16 + rl, kq);
#pragma unroll
    for (int ni = 0; ni < 4; ++ni) offB[ni] = frag_off(wcol + ni * 16 + rl, kq);

    f32x4 zero4 = {0.f, 0.f, 0.f, 0.f};
    f32x4 acc[4][4];
#pragma unroll
    for (int mi = 0; mi < 4; ++mi)
#pragma unroll
        for (int ni = 0; ni < 4; ++ni) acc[mi][ni] = zero4;

    const int nk = DDIM / 32;   // 32

#define GU_STAGE(tt, buf)                                     \
    {                                                         \
        int k0 = (tt) * 32;                                   \
        gload16(aS + k0, &As[buf][sdstA]);                    \
        gload16(bS[0] + k0, &Bs[buf][sdstB[0]]);              \
        gload16(bS[1] + k0, &Bs[buf][sdstB[1]]);              \
    }

    GU_STAGE(0, 0);
    asm volatile("s_waitcnt vmcnt(0)" ::: "memory");
    __builtin_amdgcn_s_barrier();

    int cur = 0;
    for (int t = 0; t < nk; ++t) {
        if (t + 1 < nk) GU_STAGE(t + 1, cur ^ 1);     // buffer freed by previous barrier
        const bf16* Ab = As[cur];
        const bf16* Bb = Bs[cur];
        s16x8 a[4], b[4];
#pragma unroll
        for (int mi = 0; mi < 4; ++mi) a[mi] = *reinterpret_cast<const s16x8*>(Ab + offA[mi]);
#pragma unroll
        for (int ni = 0; ni < 4; ++ni) b[ni] = *reinterpret_cast<const s16x8*>(Bb + offB[ni]);
        __builtin_amdgcn_s_setprio(1);
#pragma unroll
        for (int mi = 0; mi < 4; ++mi)
#pragma unroll
            for (int ni = 0; ni < 4; ++ni)
                acc[mi][ni] = __builtin_amdgcn_mfma_f32_16x16x32_bf16(a[mi], b[ni], acc[mi][ni], 0, 0, 0);
        __builtin_amdgcn_s_setprio(0);
        __builtin_amdgcn_sched_barrier(0);
        if (t + 1 < nk) {
            asm volatile("s_waitcnt vmcnt(0)" ::: "memory");   // stage t+1 landed under compute
            __builtin_amdgcn_s_barrier();
        }
        cur ^= 1;
    }
#undef GU_STAGE

    // epilogue: even col = gate, odd col = up; pair via shfl_xor(1), even lanes store.
    int rbase = (lane >> 4) * 4, cbase = lane & 15;
    bool evenlane = (lane & 1) == 0;
#pragma unroll
    for (int mi = 0; mi < 4; ++mi) {
#pragma unroll
        for (int ni = 0; ni < 4; ++ni) {
#pragma unroll
            for (int r = 0; r < 4; ++r) {
                float own = acc[mi][ni][r];
                float oth = __shfl_xor(own, 1);
                int row = m0 + wrow + mi * 16 + rbase + r;
                if (evenlane && row < ne) {
                    float g = own, u = oth;
                    float h = (g / (1.0f + expf(-g))) * u;
                    int hcol = (n0 + wcol + ni * 16 + cbase) >> 1;
                    hbuf[(size_t)(base + row) * HDIM + hcol] = __float2bfloat16(h);
                }
            }
        }
    }
}

// ======== pass 2: down GEMM 128(M) x 256(N), BK=32, fused atomic combine ========
// Widened N-tile quarters hbuf-staging (8 -> 4 N-tiles). y zeroed first;
// each element gets exactly 2 commutative fp32 adds -> deterministic.
__global__ __launch_bounds__(512, 2)
void down_kernel(const bf16* __restrict__ hbuf, const bf16* __restrict__ wdT,
                 const int* __restrict__ offs, const int* __restrict__ cnt,
                 const int* __restrict__ list, const float* __restrict__ slot_w,
                 float* __restrict__ y) {
    int slot0 = blockIdx.y * 128;
    if (slot0 >= offs[NEXP]) return;
    int e = find_expert(offs, slot0);
    int base = offs[e];
    int ne = cnt[e];
    int m0 = slot0 - base;
    int n0 = blockIdx.x * 256;   // d-tile

    __shared__ bf16 As[2][4096];
    __shared__ bf16 Bs[2][8192];

    int tid = threadIdx.x, lane = tid & 63, wid = tid >> 6;

    const bf16* bbase = wdT + (size_t)e * DDIM * HDIM + (size_t)n0 * HDIM;

    const bf16* aS; const bf16* bS[2];
    int sdstA, sdstB[2];
    {
        int q = wid;
        int lr = q * 8 + (lane >> 3);
        int ch = (lane & 7) ^ (lr & 7);
        int rr = 2 * lr + (ch >> 2);
        int koff = (ch & 3) * 8;
        int r = m0 + rr; if (r > ne - 1) r = ne - 1;
        aS = hbuf + (size_t)(base + r) * HDIM + koff;
        sdstA = q * 512;
    }
#pragma unroll
    for (int j = 0; j < 2; ++j) {
        int q = wid + j * 8;
        int lr = q * 8 + (lane >> 3);
        int ch = (lane & 7) ^ (lr & 7);
        int rr = 2 * lr + (ch >> 2);
        int koff = (ch & 3) * 8;
        bS[j] = bbase + (size_t)rr * HDIM + koff;
        sdstB[j] = q * 512;
    }

    int rl = lane & 15, kq = 8 * (lane >> 4);
    int wrow = (wid >> 2) * 64;
    int wcol = (wid & 3) * 64;
    int offA[4], offB[4];
#pragma unroll
    for (int mi = 0; mi < 4; ++mi) offA[mi] = frag_off(wrow + mi * 16 + rl, kq);
#pragma unroll
    for (int ni = 0; ni < 4; ++ni) offB[ni] = frag_off(wcol + ni * 16 + rl, kq);

    f32x4 zero4 = {0.f, 0.f, 0.f, 0.f};
    f32x4 acc[4][4];
#pragma unroll
    for (int mi = 0; mi < 4; ++mi)
#pragma unroll
        for (int ni = 0; ni < 4; ++ni) acc[mi][ni] = zero4;

    const int nk = HDIM / 32;   // 64

#define DN_STAGE(tt, buf)                                     \
    {                                                         \
        int k0 = (tt) * 32;                                   \
        gload16(aS + k0, &As[buf][sdstA]);                    \
        gload16(bS[0] + k0, &Bs[buf][sdstB[0]]);              \
        gload16(bS[1] + k0, &Bs[buf][sdstB[1]]);              \
    }

    DN_STAGE(0, 0);
    asm volatile("s_waitcnt vmcnt(0)" ::: "memory");
    __builtin_amdgcn_s_barrier();

    int cur = 0;
    for (int t = 0; t < nk; ++t) {
        if (t + 1 < nk) DN_STAGE(t + 1, cur ^ 1);
        const bf16* Ab = As[cur];
        const bf16* Bb = Bs[cur];
        s16x8 a[4], b[4];
#pragma unroll
        for (int mi = 0; mi < 4; ++mi) a[mi] = *reinterpret_cast<const s16x8*>(Ab + offA[mi]);
#pragma unroll
        for (int ni = 0; ni < 4; ++ni) b[ni] = *reinterpret_cast<const s16x8*>(Bb + offB[ni]);
        __builtin_amdgcn_s_setprio(1);
#pragma unroll
        for (int mi = 0; mi < 4; ++mi)
#pragma unroll
            for (int ni = 0; ni < 4; ++ni)
                acc[mi][ni] = __builtin_amdgcn_mfma_f32_16x16x32_bf16(a[mi], b[ni], acc[mi][ni], 0, 0, 0);
        __builtin_amdgcn_s_setprio(0);
        __builtin_amdgcn_sched_barrier(0);
        if (t + 1 < nk) {
            asm volatile("s_waitcnt vmcnt(0)" ::: "memory");
            __builtin_amdgcn_s_barrier();
        }
        cur ^= 1;
    }
#undef DN_STAGE

    // epilogue: y[tok][col] += w * acc  (2 adds per element, commutative -> deterministic)
    int rbase = (lane >> 4) * 4, cbase = lane & 15;
#pragma unroll
    for (int mi = 0; mi < 4; ++mi) {
#pragma unroll
        for (int r = 0; r < 4; ++r) {
            int row = m0 + wrow + mi * 16 + rbase + r;
            if (row < ne) {
                int slot = base + row;
                int tok = list[slot];
                float w = slot_w[slot];
                float* yrow = y + (size_t)tok * DDIM + n0 + wcol + cbase;
#pragma unroll
                for (int ni = 0; ni < 4; ++ni)
                    atomicAdd(yrow + ni * 16, w * acc[mi][ni][r]);
            }
        }
    }
}

extern "C" void kernel_launch(void* const* d_in, const int* in_sizes, int n_in,
                              void* d_out, int out_size, void* d_ws, size_t ws_size,
                              hipStream_t stream) {
    const float* x  = (const float*)d_in[0];
    const float* rw = (const float*)d_in[1];
    const float* wg = (const float*)d_in[2];
    const float* wu = (const float*)d_in[3];
    const float* wd = (const float*)d_in[4];
    float* y = (float*)d_out;

    char* ws = (char*)d_ws;
    int*   r_e    = (int*)  (ws + 0);           // 2T ints
    float* r_w    = (float*)(ws + 32768);       // 2T floats
    int*   offs   = (int*)  (ws + 65600);       // 9 (padded bases)
    int*   cnt    = (int*)  (ws + 65640);       // 8 real counts
    int*   list   = (int*)  (ws + 65792);       // MAXSLOT ints
    float* slot_w = (float*)(ws + 65792 + 4 * MAXSLOT);  // MAXSLOT floats
    bf16*  xb     = (bf16*) (ws + 1048576ull);      // 8 MB
    bf16*  wguT   = (bf16*) (ws + 16777216ull);     // 64 MB  [E][2H][D] interleaved g/u
    bf16*  wdT    = (bf16*) (ws + 83886080ull);     // 32 MB  [E][D][H]
    bf16*  hbuf   = (bf16*) (ws + 117440512ull);    // 37.75 MB [MAXSLOT][H]

    // weight transposes + casts (wg+wu in one launch; wd separate)
    transpose_gu_kernel<<<dim3(DDIM / 64, HDIM / 64, 2 * NEXP), 256, 0, stream>>>(wg, wu, wguT);
    transpose_wd_kernel<<<dim3(HDIM / 64, DDIM / 64, NEXP), 256, 0, stream>>>(wd, wdT);

    // routing (+ fused x cast) and padded binning
    router_cast_kernel<<<dim3(T_TOK / 4), 256, 0, stream>>>(x, rw, r_e, r_w, xb);
    binning_kernel<<<dim3(1), 512, 0, stream>>>(r_e, r_w, offs, cnt, list, slot_w);

    // zero y (down accumulates into it atomically)
    hipMemsetAsync(d_out, 0, (size_t)out_size * sizeof(float), stream);

    // expert GEMMs, compacted grids over padded slot-tiles
    gateup_kernel<<<dim3(2 * HDIM / 256, MAXSLOT / 128, 1), 512, 0, stream>>>(
        xb, wguT, offs, cnt, list, hbuf);
    down_kernel<<<dim3(DDIM / 256, MAXSLOT / 128, 1), 512, 0, stream>>>(
        hbuf, wdT, offs, cnt, list, slot_w, y);
}

// Round 15
// 284.131 us; speedup vs baseline: 1.0164x; 1.0164x over previous
//
#include <hip/hip_runtime.h>
#include <hip/hip_bf16.h>

#define T_TOK 4096
#define DDIM  1024
#define HDIM  2048
#define NEXP  8
#define MAXSLOT 9216   // 2T padded: each expert base 128-aligned

typedef __attribute__((ext_vector_type(4))) float f32x4;
typedef __attribute__((ext_vector_type(8))) short s16x8;
typedef __hip_bfloat16 bf16;

typedef const void __attribute__((address_space(1))) gvoid;
typedef void __attribute__((address_space(3))) svoid;

__device__ __forceinline__ void gload16(const void* g, void* l) {
    // async global->LDS, 16B/lane; LDS dest = wave-uniform base, HW adds lane*16
    __builtin_amdgcn_global_load_lds((gvoid*)g, (svoid*)l, 16, 0, 0);
}

// ---------------- router (fp64 acc, top-2 softmax) + fused x->bf16 cast ----------------
__global__ void router_cast_kernel(const float* __restrict__ x, const float* __restrict__ rw,
                                   int* __restrict__ r_e, float* __restrict__ r_w,
                                   bf16* __restrict__ xb) {
    int wave = threadIdx.x >> 6, lane = threadIdx.x & 63;
    int t = blockIdx.x * 4 + wave;
    const float* xr = x + (size_t)t * DDIM;
    bf16* xbr = xb + (size_t)t * DDIM;
    double acc[NEXP];
#pragma unroll
    for (int e = 0; e < NEXP; ++e) acc[e] = 0.0;
#pragma unroll
    for (int c = 0; c < 4; ++c) {
        int d = c * 256 + lane * 4;
        float4 v = *reinterpret_cast<const float4*>(xr + d);
        union { ushort4 u; bf16 h[4]; } o;
        o.h[0] = __float2bfloat16(v.x);
        o.h[1] = __float2bfloat16(v.y);
        o.h[2] = __float2bfloat16(v.z);
        o.h[3] = __float2bfloat16(v.w);
        *reinterpret_cast<ushort4*>(xbr + d) = o.u;
        const float* rw0 = rw + (size_t)d * NEXP;
#pragma unroll
        for (int j = 0; j < 4; ++j) {
            float xv = (&v.x)[j];
            const float* rwr = rw0 + j * NEXP;
#pragma unroll
            for (int e = 0; e < NEXP; ++e) acc[e] += (double)xv * (double)rwr[e];
        }
    }
#pragma unroll
    for (int e = 0; e < NEXP; ++e) {
#pragma unroll
        for (int off = 32; off > 0; off >>= 1) acc[e] += __shfl_down(acc[e], off);
    }
    if (lane == 0) {
        int i0 = 0; double v0 = acc[0];
#pragma unroll
        for (int e = 1; e < NEXP; ++e) if (acc[e] > v0) { v0 = acc[e]; i0 = e; }
        int i1 = -1; double v1 = -1e300;
#pragma unroll
        for (int e = 0; e < NEXP; ++e) { if (e == i0) continue; if (acc[e] > v1) { v1 = acc[e]; i1 = e; } }
        float w0 = 1.0f / (1.0f + expf((float)(v1 - v0)));
        float w1 = 1.0f - w0;
        r_e[2*t]   = i0; r_e[2*t+1] = i1;
        r_w[2*t]   = w0; r_w[2*t+1] = w1;
    }
}

// ------- fused binning: count + 128-ALIGNED scan + fill, one block -------
__global__ void binning_kernel(const int* __restrict__ r_e, const float* __restrict__ r_w,
                               int* __restrict__ offs, int* __restrict__ cnt,
                               int* __restrict__ list, float* __restrict__ slot_w) {
    __shared__ int scnt[NEXP], scur[NEXP], soff[NEXP + 1];
    int tid = threadIdx.x;
    if (tid < NEXP) { scnt[tid] = 0; scur[tid] = 0; }
    __syncthreads();
    for (int i = tid; i < 2 * T_TOK; i += 512) atomicAdd(&scnt[r_e[i]], 1);
    __syncthreads();
    if (tid == 0) {
        int s = 0;
        for (int e = 0; e < NEXP; ++e) { soff[e] = s; s += (scnt[e] + 127) & ~127; }
        soff[NEXP] = s;
    }
    __syncthreads();
    if (tid < NEXP + 1) offs[tid] = soff[tid];
    if (tid < NEXP) cnt[tid] = scnt[tid];
    for (int i = tid; i < 2 * T_TOK; i += 512) {
        int e = r_e[i];
        int pos = atomicAdd(&scur[e], 1);
        int slot = soff[e] + pos;
        list[slot] = i >> 1;
        slot_w[slot] = r_w[i];
    }
}

// -------- wg+wu transpose+cast in ONE launch: z in [0,16), which = z>>3 --------
__global__ void transpose_gu_kernel(const float* __restrict__ wg, const float* __restrict__ wu,
                                    bf16* __restrict__ wguT) {
    __shared__ bf16 tile[64][68];
    int which = blockIdx.z >> 3;            // 0 = gate, 1 = up
    int e = blockIdx.z & 7;
    const float* inp = (which ? wu : wg) + (size_t)e * DDIM * HDIM;
    bf16* outp = wguT + (size_t)e * 2 * HDIM * DDIM;
    int r0 = blockIdx.x * 64, c0 = blockIdx.y * 64;   // r over D, c over H
    int tid = threadIdx.x;
#pragma unroll
    for (int i = 0; i < 4; ++i) {
        int idx = i * 256 + tid;
        int r = idx >> 4, c4 = (idx & 15) * 4;
        float4 v = *reinterpret_cast<const float4*>(inp + (size_t)(r0 + r) * HDIM + c0 + c4);
        union { ushort4 u; bf16 h[4]; } o;
        o.h[0] = __float2bfloat16(v.x);
        o.h[1] = __float2bfloat16(v.y);
        o.h[2] = __float2bfloat16(v.z);
        o.h[3] = __float2bfloat16(v.w);
        *reinterpret_cast<ushort4*>(&tile[r][c4]) = o.u;
    }
    __syncthreads();
#pragma unroll
    for (int i = 0; i < 4; ++i) {
        int idx = i * 256 + tid;
        int c = idx >> 4, r4 = (idx & 15) * 4;
        union { ushort4 u; bf16 h[4]; } w;
        w.h[0] = tile[r4 + 0][c];
        w.h[1] = tile[r4 + 1][c];
        w.h[2] = tile[r4 + 2][c];
        w.h[3] = tile[r4 + 3][c];
        *reinterpret_cast<ushort4*>(outp + ((size_t)(c0 + c) * 2 + which) * DDIM + r0 + r4) = w.u;
    }
}

// -------- wd transpose+cast: [E][H][D] -> [E][D][H] --------
__global__ void transpose_wd_kernel(const float* __restrict__ wd, bf16* __restrict__ wdT) {
    __shared__ bf16 tile[64][68];
    const float* inp = wd + (size_t)blockIdx.z * HDIM * DDIM;
    bf16* outp = wdT + (size_t)blockIdx.z * DDIM * HDIM;
    int r0 = blockIdx.x * 64, c0 = blockIdx.y * 64;   // r over H, c over D
    int tid = threadIdx.x;
#pragma unroll
    for (int i = 0; i < 4; ++i) {
        int idx = i * 256 + tid;
        int r = idx >> 4, c4 = (idx & 15) * 4;
        float4 v = *reinterpret_cast<const float4*>(inp + (size_t)(r0 + r) * DDIM + c0 + c4);
        union { ushort4 u; bf16 h[4]; } o;
        o.h[0] = __float2bfloat16(v.x);
        o.h[1] = __float2bfloat16(v.y);
        o.h[2] = __float2bfloat16(v.z);
        o.h[3] = __float2bfloat16(v.w);
        *reinterpret_cast<ushort4*>(&tile[r][c4]) = o.u;
    }
    __syncthreads();
#pragma unroll
    for (int i = 0; i < 4; ++i) {
        int idx = i * 256 + tid;
        int c = idx >> 4, r4 = (idx & 15) * 4;
        union { ushort4 u; bf16 h[4]; } w;
        w.h[0] = tile[r4 + 0][c];
        w.h[1] = tile[r4 + 1][c];
        w.h[2] = tile[r4 + 2][c];
        w.h[3] = tile[r4 + 3][c];
        *reinterpret_cast<ushort4*>(outp + (size_t)(c0 + c) * HDIM + r0 + r4) = w.u;
    }
}

// expert lookup in padded slot space
__device__ __forceinline__ int find_expert(const int* offs, int slot0) {
    int e = 0;
#pragma unroll
    for (int i = 0; i < NEXP - 1; ++i) e += (offs[e + 1] <= slot0) ? 1 : 0;
    return e;
}

// ======== pass 1: gate+up as ONE GEMM over interleaved wguT [2H][D] ========
// EXACT R4 geometry (best-measured gateup, 116.9 us): 128(M) x 128(N-in-2H),
// BK=64, 8 waves (2M x 4N, wave-out 64x32, acc[4][2]). 64 KB dbuf LDS (2 blk/CU).
// Counted vmcnt(4) at loop head (tile t+1 landed, t+2's 4 loads in flight).
// Linear-row LDS [row][64] with chunk-XOR swizzle (0 conflicts, R4-measured).
__global__ __launch_bounds__(512, 2)
void gateup_kernel(const bf16* __restrict__ xb, const bf16* __restrict__ wguT,
                   const int* __restrict__ offs, const int* __restrict__ cnt,
                   const int* __restrict__ list, bf16* __restrict__ hbuf) {
    int slot0 = blockIdx.y * 128;
    if (slot0 >= offs[NEXP]) return;
    int e = find_expert(offs, slot0);
    int base = offs[e];
    int ne = cnt[e];
    int m0 = slot0 - base;
    int n0 = blockIdx.x * 128;       // in 2H=4096 interleaved space

    __shared__ bf16 As[2][8192];     // 128 rows x 64 k (16 KB/buf)
    __shared__ bf16 Bs[2][8192];

    int tid = threadIdx.x, lane = tid & 63, wid = tid >> 6;   // 8 waves
    int sub = lane >> 3;                       // 0..7
    int koff = 8 * ((lane & 7) ^ sub);         // inverse-swizzled source chunk (row&7 == sub)

    const bf16* bbase = wguT + (size_t)e * (2 * HDIM) * DDIM + (size_t)n0 * DDIM;

    // staging: 2 A-issues + 2 B-issues per wave (q = wid, wid+8), each 1 KB
    const bf16* aS[2]; const bf16* bS[2];
    int sdst[2];
#pragma unroll
    for (int j = 0; j < 2; ++j) {
        int q = wid + j * 8;                   // 0..15
        int row = q * 8 + sub;                 // [0,128)
        int r = m0 + row; if (r > ne - 1) r = ne - 1;   // clamp: read-only, never stored
        aS[j] = xb + (size_t)list[base + r] * DDIM + koff;
        bS[j] = bbase + (size_t)row * DDIM + koff;
        sdst[j] = q * 512;                     // wave-uniform elem offset
    }

    int rl = lane & 15, kq = 8 * (lane >> 4);
    int wrow = (wid >> 2) * 64;      // 2 M waves
    int wcol = (wid & 3) * 32;       // 4 N waves
    int xorv = (rl & 7) * 8;         // read-side swizzle (row&7 == rl&7 for 16-aligned bases)

    f32x4 zero4 = {0.f, 0.f, 0.f, 0.f};
    f32x4 acc[4][2];
#pragma unroll
    for (int mi = 0; mi < 4; ++mi) { acc[mi][0] = zero4; acc[mi][1] = zero4; }

    const int nk = DDIM / 64;   // 16

#define GU_STAGE(tt, buf)                                     \
    {                                                         \
        int k0 = (tt) * 64;                                   \
        gload16(aS[0] + k0, &As[buf][sdst[0]]);               \
        gload16(aS[1] + k0, &As[buf][sdst[1]]);               \
        gload16(bS[0] + k0, &Bs[buf][sdst[0]]);               \
        gload16(bS[1] + k0, &Bs[buf][sdst[1]]);               \
    }

#define GU_COMPUTE(Ab, Bb)                                                        \
    _Pragma("unroll")                                                             \
    for (int kk = 0; kk < 2; ++kk) {                                              \
        int kos = (kk * 32 + kq) ^ xorv;                                          \
        s16x8 a[4], b[2];                                                         \
        _Pragma("unroll")                                                         \
        for (int mi = 0; mi < 4; ++mi)                                            \
            a[mi] = *reinterpret_cast<const s16x8*>(&(Ab)[(wrow + mi * 16 + rl) * 64 + kos]); \
        _Pragma("unroll")                                                         \
        for (int ni = 0; ni < 2; ++ni)                                            \
            b[ni] = *reinterpret_cast<const s16x8*>(&(Bb)[(wcol + ni * 16 + rl) * 64 + kos]); \
        __builtin_amdgcn_s_setprio(1);                                            \
        _Pragma("unroll")                                                         \
        for (int mi = 0; mi < 4; ++mi)                                            \
            _Pragma("unroll")                                                     \
            for (int ni = 0; ni < 2; ++ni)                                        \
                acc[mi][ni] = __builtin_amdgcn_mfma_f32_16x16x32_bf16(a[mi], b[ni], acc[mi][ni], 0, 0, 0); \
        __builtin_amdgcn_s_setprio(0);                                            \
    }

    // prologue: stage tiles 0,1 (4 loads each)
    GU_STAGE(0, 0);
    GU_STAGE(1, 1);

    for (int t = 0; t < nk; ++t) {
        if (t + 1 < nk) asm volatile("s_waitcnt vmcnt(4)" ::: "memory");   // tile t landed
        else            asm volatile("s_waitcnt vmcnt(0)" ::: "memory");
        __builtin_amdgcn_s_barrier();
        GU_COMPUTE(As[t & 1], Bs[t & 1]);
        __builtin_amdgcn_sched_barrier(0);
        __builtin_amdgcn_s_barrier();                 // buf[t&1] free
        if (t + 2 < nk) GU_STAGE(t + 2, t & 1);       // in flight: t+1(4) + t+2(4)
    }
#undef GU_COMPUTE
#undef GU_STAGE

    // epilogue: even col = gate, odd col = up; pair via shfl_xor(1), even lanes store.
    int rbase = (lane >> 4) * 4, cbase = lane & 15;
    bool evenlane = (lane & 1) == 0;
#pragma unroll
    for (int mi = 0; mi < 4; ++mi) {
#pragma unroll
        for (int ni = 0; ni < 2; ++ni) {
#pragma unroll
            for (int r = 0; r < 4; ++r) {
                float own = acc[mi][ni][r];
                float oth = __shfl_xor(own, 1);
                int row = m0 + wrow + mi * 16 + rbase + r;
                if (evenlane && row < ne) {
                    float g = own, u = oth;
                    float h = (g / (1.0f + expf(-g))) * u;
                    int hcol = (n0 + wcol + ni * 16 + cbase) >> 1;
                    hbuf[(size_t)(base + row) * HDIM + hcol] = __float2bfloat16(h);
                }
            }
        }
    }
}

// ======== pass 2: down GEMM, R4 structure at 128x128, BK=64 (32 iters), ========
// 8 waves acc[4][2], counted vmcnt(4), fused deterministic atomic combine.
// y zeroed first; each element gets exactly 2 commutative fp32 adds.
__global__ __launch_bounds__(512, 2)
void down_kernel(const bf16* __restrict__ hbuf, const bf16* __restrict__ wdT,
                 const int* __restrict__ offs, const int* __restrict__ cnt,
                 const int* __restrict__ list, const float* __restrict__ slot_w,
                 float* __restrict__ y) {
    int slot0 = blockIdx.y * 128;
    if (slot0 >= offs[NEXP]) return;
    int e = find_expert(offs, slot0);
    int base = offs[e];
    int ne = cnt[e];
    int m0 = slot0 - base;
    int n0 = blockIdx.x * 128;   // d-tile

    __shared__ bf16 As[2][8192];
    __shared__ bf16 Bs[2][8192];

    int tid = threadIdx.x, lane = tid & 63, wid = tid >> 6;
    int sub = lane >> 3;
    int koff = 8 * ((lane & 7) ^ sub);

    const bf16* bbase = wdT + (size_t)e * DDIM * HDIM + (size_t)n0 * HDIM;

    const bf16* aS[2]; const bf16* bS[2];
    int sdst[2];
#pragma unroll
    for (int j = 0; j < 2; ++j) {
        int q = wid + j * 8;
        int row = q * 8 + sub;
        int r = m0 + row; if (r > ne - 1) r = ne - 1;
        aS[j] = hbuf + (size_t)(base + r) * HDIM + koff;
        bS[j] = bbase + (size_t)row * HDIM + koff;
        sdst[j] = q * 512;
    }

    int rl = lane & 15, kq = 8 * (lane >> 4);
    int wrow = (wid >> 2) * 64;
    int wcol = (wid & 3) * 32;
    int xorv = (rl & 7) * 8;

    f32x4 zero4 = {0.f, 0.f, 0.f, 0.f};
    f32x4 acc[4][2];
#pragma unroll
    for (int mi = 0; mi < 4; ++mi) { acc[mi][0] = zero4; acc[mi][1] = zero4; }

    const int nk = HDIM / 64;   // 32

#define DN_STAGE(tt, buf)                                     \
    {                                                         \
        int k0 = (tt) * 64;                                   \
        gload16(aS[0] + k0, &As[buf][sdst[0]]);               \
        gload16(aS[1] + k0, &As[buf][sdst[1]]);               \
        gload16(bS[0] + k0, &Bs[buf][sdst[0]]);               \
        gload16(bS[1] + k0, &Bs[buf][sdst[1]]);               \
    }

#define DN_COMPUTE(Ab, Bb)                                                        \
    _Pragma("unroll")                                                             \
    for (int kk = 0; kk < 2; ++kk) {                                              \
        int kos = (kk * 32 + kq) ^ xorv;                                          \
        s16x8 a[4], b[2];                                                         \
        _Pragma("unroll")                                                         \
        for (int mi = 0; mi < 4; ++mi)                                            \
            a[mi] = *reinterpret_cast<const s16x8*>(&(Ab)[(wrow + mi * 16 + rl) * 64 + kos]); \
        _Pragma("unroll")                                                         \
        for (int ni = 0; ni < 2; ++ni)                                            \
            b[ni] = *reinterpret_cast<const s16x8*>(&(Bb)[(wcol + ni * 16 + rl) * 64 + kos]); \
        __builtin_amdgcn_s_setprio(1);                                            \
        _Pragma("unroll")                                                         \
        for (int mi = 0; mi < 4; ++mi)                                            \
            _Pragma("unroll")                                                     \
            for (int ni = 0; ni < 2; ++ni)                                        \
                acc[mi][ni] = __builtin_amdgcn_mfma_f32_16x16x32_bf16(a[mi], b[ni], acc[mi][ni], 0, 0, 0); \
        __builtin_amdgcn_s_setprio(0);                                            \
    }

    DN_STAGE(0, 0);
    DN_STAGE(1, 1);

    for (int t = 0; t < nk; ++t) {
        if (t + 1 < nk) asm volatile("s_waitcnt vmcnt(4)" ::: "memory");
        else            asm volatile("s_waitcnt vmcnt(0)" ::: "memory");
        __builtin_amdgcn_s_barrier();
        DN_COMPUTE(As[t & 1], Bs[t & 1]);
        __builtin_amdgcn_sched_barrier(0);
        __builtin_amdgcn_s_barrier();
        if (t + 2 < nk) DN_STAGE(t + 2, t & 1);
    }
#undef DN_COMPUTE
#undef DN_STAGE

    // epilogue: y[tok][col] += w * acc  (2 adds per element, commutative -> deterministic)
    int rbase = (lane >> 4) * 4, cbase = lane & 15;
#pragma unroll
    for (int mi = 0; mi < 4; ++mi) {
#pragma unroll
        for (int r = 0; r < 4; ++r) {
            int row = m0 + wrow + mi * 16 + rbase + r;
            if (row < ne) {
                int slot = base + row;
                int tok = list[slot];
                float w = slot_w[slot];
                float* yrow = y + (size_t)tok * DDIM + n0 + wcol + cbase;
#pragma unroll
                for (int ni = 0; ni < 2; ++ni)
                    atomicAdd(yrow + ni * 16, w * acc[mi][ni][r]);
            }
        }
    }
}

extern "C" void kernel_launch(void* const* d_in, const int* in_sizes, int n_in,
                              void* d_out, int out_size, void* d_ws, size_t ws_size,
                              hipStream_t stream) {
    const float* x  = (const float*)d_in[0];
    const float* rw = (const float*)d_in[1];
    const float* wg = (const float*)d_in[2];
    const float* wu = (const float*)d_in[3];
    const float* wd = (const float*)d_in[4];
    float* y = (float*)d_out;

    char* ws = (char*)d_ws;
    int*   r_e    = (int*)  (ws + 0);           // 2T ints
    float* r_w    = (float*)(ws + 32768);       // 2T floats
    int*   offs   = (int*)  (ws + 65600);       // 9 (padded bases)
    int*   cnt    = (int*)  (ws + 65640);       // 8 real counts
    int*   list   = (int*)  (ws + 65792);       // MAXSLOT ints
    float* slot_w = (float*)(ws + 65792 + 4 * MAXSLOT);  // MAXSLOT floats
    bf16*  xb     = (bf16*) (ws + 1048576ull);      // 8 MB
    bf16*  wguT   = (bf16*) (ws + 16777216ull);     // 64 MB  [E][2H][D] interleaved g/u
    bf16*  wdT    = (bf16*) (ws + 83886080ull);     // 32 MB  [E][D][H]
    bf16*  hbuf   = (bf16*) (ws + 117440512ull);    // 37.75 MB [MAXSLOT][H]

    // weight transposes + casts (wg+wu in one launch; wd separate)
    transpose_gu_kernel<<<dim3(DDIM / 64, HDIM / 64, 2 * NEXP), 256, 0, stream>>>(wg, wu, wguT);
    transpose_wd_kernel<<<dim3(HDIM / 64, DDIM / 64, NEXP), 256, 0, stream>>>(wd, wdT);

    // routing (+ fused x cast) and padded binning
    router_cast_kernel<<<dim3(T_TOK / 4), 256, 0, stream>>>(x, rw, r_e, r_w, xb);
    binning_kernel<<<dim3(1), 512, 0, stream>>>(r_e, r_w, offs, cnt, list, slot_w);

    // zero y (down accumulates into it atomically)
    hipMemsetAsync(d_out, 0, (size_t)out_size * sizeof(float), stream);

    // expert GEMMs, compacted grids over padded slot-tiles
    gateup_kernel<<<dim3(2 * HDIM / 128, MAXSLOT / 128, 1), 512, 0, stream>>>(
        xb, wguT, offs, cnt, list, hbuf);
    down_kernel<<<dim3(DDIM / 128, MAXSLOT / 128, 1), 512, 0, stream>>>(
        hbuf, wdT, offs, cnt, list, slot_w, y);
}

// Round 16
// 278.044 us; speedup vs baseline: 1.0386x; 1.0219x over previous
//
#include <hip/hip_runtime.h>
#include <hip/hip_bf16.h>

#define T_TOK 4096
#define DDIM  1024
#define HDIM  2048
#define NEXP  8
#define MAXSLOT 9216   // 2T padded: each expert base 128-aligned

typedef __attribute__((ext_vector_type(4))) float f32x4;
typedef __attribute__((ext_vector_type(8))) short s16x8;
typedef __hip_bfloat16 bf16;

typedef const void __attribute__((address_space(1))) gvoid;
typedef void __attribute__((address_space(3))) svoid;

__device__ __forceinline__ void gload16(const void* g, void* l) {
    // async global->LDS, 16B/lane; LDS dest = wave-uniform base, HW adds lane*16
    __builtin_amdgcn_global_load_lds((gvoid*)g, (svoid*)l, 16, 0, 0);
}

// ---------------- router (fp64 acc, top-2 softmax) + fused x->bf16 cast + y-zero ------
__global__ void router_cast_kernel(const float* __restrict__ x, const float* __restrict__ rw,
                                   int* __restrict__ r_e, float* __restrict__ r_w,
                                   bf16* __restrict__ xb, float* __restrict__ y) {
    // zero this block's 4096-float slice of y (replaces hipMemsetAsync dispatch)
    {
        float4 z4 = {0.f, 0.f, 0.f, 0.f};
        size_t ybase = (size_t)blockIdx.x * 4096 + threadIdx.x * 4;
#pragma unroll
        for (int i = 0; i < 4; ++i)
            *reinterpret_cast<float4*>(y + ybase + (size_t)i * 1024) = z4;
    }
    int wave = threadIdx.x >> 6, lane = threadIdx.x & 63;
    int t = blockIdx.x * 4 + wave;
    const float* xr = x + (size_t)t * DDIM;
    bf16* xbr = xb + (size_t)t * DDIM;
    double acc[NEXP];
#pragma unroll
    for (int e = 0; e < NEXP; ++e) acc[e] = 0.0;
#pragma unroll
    for (int c = 0; c < 4; ++c) {
        int d = c * 256 + lane * 4;
        float4 v = *reinterpret_cast<const float4*>(xr + d);
        union { ushort4 u; bf16 h[4]; } o;
        o.h[0] = __float2bfloat16(v.x);
        o.h[1] = __float2bfloat16(v.y);
        o.h[2] = __float2bfloat16(v.z);
        o.h[3] = __float2bfloat16(v.w);
        *reinterpret_cast<ushort4*>(xbr + d) = o.u;
        const float* rw0 = rw + (size_t)d * NEXP;
#pragma unroll
        for (int j = 0; j < 4; ++j) {
            float xv = (&v.x)[j];
            const float* rwr = rw0 + j * NEXP;
#pragma unroll
            for (int e = 0; e < NEXP; ++e) acc[e] += (double)xv * (double)rwr[e];
        }
    }
#pragma unroll
    for (int e = 0; e < NEXP; ++e) {
#pragma unroll
        for (int off = 32; off > 0; off >>= 1) acc[e] += __shfl_down(acc[e], off);
    }
    if (lane == 0) {
        int i0 = 0; double v0 = acc[0];
#pragma unroll
        for (int e = 1; e < NEXP; ++e) if (acc[e] > v0) { v0 = acc[e]; i0 = e; }
        int i1 = -1; double v1 = -1e300;
#pragma unroll
        for (int e = 0; e < NEXP; ++e) { if (e == i0) continue; if (acc[e] > v1) { v1 = acc[e]; i1 = e; } }
        float w0 = 1.0f / (1.0f + expf((float)(v1 - v0)));
        float w1 = 1.0f - w0;
        r_e[2*t]   = i0; r_e[2*t+1] = i1;
        r_w[2*t]   = w0; r_w[2*t+1] = w1;
    }
}

// ------- fused binning: count + 128-ALIGNED scan + fill, one block -------
__global__ void binning_kernel(const int* __restrict__ r_e, const float* __restrict__ r_w,
                               int* __restrict__ offs, int* __restrict__ cnt,
                               int* __restrict__ list, float* __restrict__ slot_w) {
    __shared__ int scnt[NEXP], scur[NEXP], soff[NEXP + 1];
    int tid = threadIdx.x;
    if (tid < NEXP) { scnt[tid] = 0; scur[tid] = 0; }
    __syncthreads();
    for (int i = tid; i < 2 * T_TOK; i += 512) atomicAdd(&scnt[r_e[i]], 1);
    __syncthreads();
    if (tid == 0) {
        int s = 0;
        for (int e = 0; e < NEXP; ++e) { soff[e] = s; s += (scnt[e] + 127) & ~127; }
        soff[NEXP] = s;
    }
    __syncthreads();
    if (tid < NEXP + 1) offs[tid] = soff[tid];
    if (tid < NEXP) cnt[tid] = scnt[tid];
    for (int i = tid; i < 2 * T_TOK; i += 512) {
        int e = r_e[i];
        int pos = atomicAdd(&scur[e], 1);
        int slot = soff[e] + pos;
        list[slot] = i >> 1;
        slot_w[slot] = r_w[i];
    }
}

// -------- ALL weight transposes in one launch, conflict-free swizzled LDS tile --------
// flat 1D grid: bid < 8192 -> wg/wu (which = bid/4096? no: z = bid/512 in [0,16),
// which = z>>3, e = z&7); bid >= 8192 -> wd (e = (bid-8192)/512).
// Tile swizzle: elem (r,c) at r*64 + 4*((c>>2) ^ sw(r)) + (c&3),
// sw(r) = ((r>>2) ^ ((r&3)<<2)) & 15.  Write: 32-bank clean; read: 16 distinct
// banks per 16-lane group (derivation in R16 notes) -> 0 conflicts both phases.
__device__ __forceinline__ int sw_r(int r) { return ((r >> 2) ^ ((r & 3) << 2)) & 15; }

__global__ void transpose_all_kernel(const float* __restrict__ wg, const float* __restrict__ wu,
                                     const float* __restrict__ wd,
                                     bf16* __restrict__ wguT, bf16* __restrict__ wdT) {
    __shared__ __align__(16) bf16 tile[64 * 64];
    int bid = blockIdx.x;
    const float* inp; bf16* outp; int C, OS, r0, c0;
    if (bid < 8192) {
        int z = bid >> 9;              // [0,16)
        int t = bid & 511;
        int which = z >> 3, e = z & 7;
        inp = (which ? wu : wg) + (size_t)e * DDIM * HDIM;   // [D][H]
        outp = wguT + (size_t)e * 2 * HDIM * DDIM + (size_t)which * DDIM;
        C = HDIM; OS = 2 * DDIM;
        r0 = (t >> 5) * 64;            // 16 r-tiles over D
        c0 = (t & 31) * 64;            // 32 c-tiles over H
    } else {
        int b2 = bid - 8192;
        int e = b2 >> 9;
        int t = b2 & 511;
        inp = wd + (size_t)e * HDIM * DDIM;                  // [H][D]
        outp = wdT + (size_t)e * DDIM * HDIM;
        C = DDIM; OS = HDIM;
        r0 = (t >> 4) * 64;            // 32 r-tiles over H
        c0 = (t & 15) * 64;            // 16 c-tiles over D
    }
    int tid = threadIdx.x;
#pragma unroll
    for (int i = 0; i < 4; ++i) {
        int idx = i * 256 + tid;
        int r = idx >> 4, c4 = (idx & 15) * 4;
        float4 v = *reinterpret_cast<const float4*>(inp + (size_t)(r0 + r) * C + c0 + c4);
        union { ushort4 u; bf16 h[4]; } o;
        o.h[0] = __float2bfloat16(v.x);
        o.h[1] = __float2bfloat16(v.y);
        o.h[2] = __float2bfloat16(v.z);
        o.h[3] = __float2bfloat16(v.w);
        *reinterpret_cast<ushort4*>(&tile[r * 64 + 4 * ((c4 >> 2) ^ sw_r(r))]) = o.u;
    }
    __syncthreads();
#pragma unroll
    for (int i = 0; i < 4; ++i) {
        int idx = i * 256 + tid;
        int c = idx >> 4, r4 = (idx & 15) * 4;
        int g = c >> 2, ce = c & 3;
        union { ushort4 u; bf16 h[4]; } w;
#pragma unroll
        for (int j = 0; j < 4; ++j) {
            int r = r4 + j;
            w.h[j] = tile[r * 64 + 4 * (g ^ sw_r(r)) + ce];
        }
        *reinterpret_cast<ushort4*>(outp + (size_t)(c0 + c) * OS + r0 + r4) = w.u;
    }
}

// expert lookup in padded slot space
__device__ __forceinline__ int find_expert(const int* offs, int slot0) {
    int e = 0;
#pragma unroll
    for (int i = 0; i < NEXP - 1; ++i) e += (offs[e + 1] <= slot0) ? 1 : 0;
    return e;
}

// ======== pass 1: gate+up as ONE GEMM over interleaved wguT [2H][D] ========
// R4/R15 geometry (best-measured): 128(M) x 128(N-in-2H), BK=64, 8 waves
// (2M x 4N, wave-out 64x32, acc[4][2]). 64 KB dbuf LDS. Counted vmcnt(4).
__global__ __launch_bounds__(512, 2)
void gateup_kernel(const bf16* __restrict__ xb, const bf16* __restrict__ wguT,
                   const int* __restrict__ offs, const int* __restrict__ cnt,
                   const int* __restrict__ list, bf16* __restrict__ hbuf) {
    int slot0 = blockIdx.y * 128;
    if (slot0 >= offs[NEXP]) return;
    int e = find_expert(offs, slot0);
    int base = offs[e];
    int ne = cnt[e];
    int m0 = slot0 - base;
    int n0 = blockIdx.x * 128;       // in 2H=4096 interleaved space

    __shared__ bf16 As[2][8192];     // 128 rows x 64 k (16 KB/buf)
    __shared__ bf16 Bs[2][8192];

    int tid = threadIdx.x, lane = tid & 63, wid = tid >> 6;   // 8 waves
    int sub = lane >> 3;                       // 0..7
    int koff = 8 * ((lane & 7) ^ sub);         // inverse-swizzled source chunk (row&7 == sub)

    const bf16* bbase = wguT + (size_t)e * (2 * HDIM) * DDIM + (size_t)n0 * DDIM;

    const bf16* aS[2]; const bf16* bS[2];
    int sdst[2];
#pragma unroll
    for (int j = 0; j < 2; ++j) {
        int q = wid + j * 8;                   // 0..15
        int row = q * 8 + sub;                 // [0,128)
        int r = m0 + row; if (r > ne - 1) r = ne - 1;   // clamp: read-only, never stored
        aS[j] = xb + (size_t)list[base + r] * DDIM + koff;
        bS[j] = bbase + (size_t)row * DDIM + koff;
        sdst[j] = q * 512;                     // wave-uniform elem offset
    }

    int rl = lane & 15, kq = 8 * (lane >> 4);
    int wrow = (wid >> 2) * 64;      // 2 M waves
    int wcol = (wid & 3) * 32;       // 4 N waves
    int xorv = (rl & 7) * 8;         // read-side swizzle

    f32x4 zero4 = {0.f, 0.f, 0.f, 0.f};
    f32x4 acc[4][2];
#pragma unroll
    for (int mi = 0; mi < 4; ++mi) { acc[mi][0] = zero4; acc[mi][1] = zero4; }

    const int nk = DDIM / 64;   // 16

#define GU_STAGE(tt, buf)                                     \
    {                                                         \
        int k0 = (tt) * 64;                                   \
        gload16(aS[0] + k0, &As[buf][sdst[0]]);               \
        gload16(aS[1] + k0, &As[buf][sdst[1]]);               \
        gload16(bS[0] + k0, &Bs[buf][sdst[0]]);               \
        gload16(bS[1] + k0, &Bs[buf][sdst[1]]);               \
    }

#define GU_COMPUTE(Ab, Bb)                                                        \
    _Pragma("unroll")                                                             \
    for (int kk = 0; kk < 2; ++kk) {                                              \
        int kos = (kk * 32 + kq) ^ xorv;                                          \
        s16x8 a[4], b[2];                                                         \
        _Pragma("unroll")                                                         \
        for (int mi = 0; mi < 4; ++mi)                                            \
            a[mi] = *reinterpret_cast<const s16x8*>(&(Ab)[(wrow + mi * 16 + rl) * 64 + kos]); \
        _Pragma("unroll")                                                         \
        for (int ni = 0; ni < 2; ++ni)                                            \
            b[ni] = *reinterpret_cast<const s16x8*>(&(Bb)[(wcol + ni * 16 + rl) * 64 + kos]); \
        __builtin_amdgcn_s_setprio(1);                                            \
        _Pragma("unroll")                                                         \
        for (int mi = 0; mi < 4; ++mi)                                            \
            _Pragma("unroll")                                                     \
            for (int ni = 0; ni < 2; ++ni)                                        \
                acc[mi][ni] = __builtin_amdgcn_mfma_f32_16x16x32_bf16(a[mi], b[ni], acc[mi][ni], 0, 0, 0); \
        __builtin_amdgcn_s_setprio(0);                                            \
    }

    GU_STAGE(0, 0);
    GU_STAGE(1, 1);

    for (int t = 0; t < nk; ++t) {
        if (t + 1 < nk) asm volatile("s_waitcnt vmcnt(4)" ::: "memory");   // tile t landed
        else            asm volatile("s_waitcnt vmcnt(0)" ::: "memory");
        __builtin_amdgcn_s_barrier();
        GU_COMPUTE(As[t & 1], Bs[t & 1]);
        __builtin_amdgcn_sched_barrier(0);
        __builtin_amdgcn_s_barrier();                 // buf[t&1] free
        if (t + 2 < nk) GU_STAGE(t + 2, t & 1);       // in flight: t+1(4) + t+2(4)
    }
#undef GU_COMPUTE
#undef GU_STAGE

    // epilogue: even col = gate, odd col = up; pair via shfl_xor(1), even lanes store.
    int rbase = (lane >> 4) * 4, cbase = lane & 15;
    bool evenlane = (lane & 1) == 0;
#pragma unroll
    for (int mi = 0; mi < 4; ++mi) {
#pragma unroll
        for (int ni = 0; ni < 2; ++ni) {
#pragma unroll
            for (int r = 0; r < 4; ++r) {
                float own = acc[mi][ni][r];
                float oth = __shfl_xor(own, 1);
                int row = m0 + wrow + mi * 16 + rbase + r;
                if (evenlane && row < ne) {
                    float g = own, u = oth;
                    float h = (g / (1.0f + expf(-g))) * u;
                    int hcol = (n0 + wcol + ni * 16 + cbase) >> 1;
                    hbuf[(size_t)(base + row) * HDIM + hcol] = __float2bfloat16(h);
                }
            }
        }
    }
}

// ======== pass 2: down GEMM, R15 structure at 128x128, BK=64 (32 iters) ========
__global__ __launch_bounds__(512, 2)
void down_kernel(const bf16* __restrict__ hbuf, const bf16* __restrict__ wdT,
                 const int* __restrict__ offs, const int* __restrict__ cnt,
                 const int* __restrict__ list, const float* __restrict__ slot_w,
                 float* __restrict__ y) {
    int slot0 = blockIdx.y * 128;
    if (slot0 >= offs[NEXP]) return;
    int e = find_expert(offs, slot0);
    int base = offs[e];
    int ne = cnt[e];
    int m0 = slot0 - base;
    int n0 = blockIdx.x * 128;   // d-tile

    __shared__ bf16 As[2][8192];
    __shared__ bf16 Bs[2][8192];

    int tid = threadIdx.x, lane = tid & 63, wid = tid >> 6;
    int sub = lane >> 3;
    int koff = 8 * ((lane & 7) ^ sub);

    const bf16* bbase = wdT + (size_t)e * DDIM * HDIM + (size_t)n0 * HDIM;

    const bf16* aS[2]; const bf16* bS[2];
    int sdst[2];
#pragma unroll
    for (int j = 0; j < 2; ++j) {
        int q = wid + j * 8;
        int row = q * 8 + sub;
        int r = m0 + row; if (r > ne - 1) r = ne - 1;
        aS[j] = hbuf + (size_t)(base + r) * HDIM + koff;
        bS[j] = bbase + (size_t)row * HDIM + koff;
        sdst[j] = q * 512;
    }

    int rl = lane & 15, kq = 8 * (lane >> 4);
    int wrow = (wid >> 2) * 64;
    int wcol = (wid & 3) * 32;
    int xorv = (rl & 7) * 8;

    f32x4 zero4 = {0.f, 0.f, 0.f, 0.f};
    f32x4 acc[4][2];
#pragma unroll
    for (int mi = 0; mi < 4; ++mi) { acc[mi][0] = zero4; acc[mi][1] = zero4; }

    const int nk = HDIM / 64;   // 32

#define DN_STAGE(tt, buf)                                     \
    {                                                         \
        int k0 = (tt) * 64;                                   \
        gload16(aS[0] + k0, &As[buf][sdst[0]]);               \
        gload16(aS[1] + k0, &As[buf][sdst[1]]);               \
        gload16(bS[0] + k0, &Bs[buf][sdst[0]]);               \
        gload16(bS[1] + k0, &Bs[buf][sdst[1]]);               \
    }

#define DN_COMPUTE(Ab, Bb)                                                        \
    _Pragma("unroll")                                                             \
    for (int kk = 0; kk < 2; ++kk) {                                              \
        int kos = (kk * 32 + kq) ^ xorv;                                          \
        s16x8 a[4], b[2];                                                         \
        _Pragma("unroll")                                                         \
        for (int mi = 0; mi < 4; ++mi)                                            \
            a[mi] = *reinterpret_cast<const s16x8*>(&(Ab)[(wrow + mi * 16 + rl) * 64 + kos]); \
        _Pragma("unroll")                                                         \
        for (int ni = 0; ni < 2; ++ni)                                            \
            b[ni] = *reinterpret_cast<const s16x8*>(&(Bb)[(wcol + ni * 16 + rl) * 64 + kos]); \
        __builtin_amdgcn_s_setprio(1);                                            \
        _Pragma("unroll")                                                         \
        for (int mi = 0; mi < 4; ++mi)                                            \
            _Pragma("unroll")                                                     \
            for (int ni = 0; ni < 2; ++ni)                                        \
                acc[mi][ni] = __builtin_amdgcn_mfma_f32_16x16x32_bf16(a[mi], b[ni], acc[mi][ni], 0, 0, 0); \
        __builtin_amdgcn_s_setprio(0);                                            \
    }

    DN_STAGE(0, 0);
    DN_STAGE(1, 1);

    for (int t = 0; t < nk; ++t) {
        if (t + 1 < nk) asm volatile("s_waitcnt vmcnt(4)" ::: "memory");
        else            asm volatile("s_waitcnt vmcnt(0)" ::: "memory");
        __builtin_amdgcn_s_barrier();
        DN_COMPUTE(As[t & 1], Bs[t & 1]);
        __builtin_amdgcn_sched_barrier(0);
        __builtin_amdgcn_s_barrier();
        if (t + 2 < nk) DN_STAGE(t + 2, t & 1);
    }
#undef DN_COMPUTE
#undef DN_STAGE

    // epilogue: y[tok][col] += w * acc  (2 adds per element, commutative -> deterministic)
    int rbase = (lane >> 4) * 4, cbase = lane & 15;
#pragma unroll
    for (int mi = 0; mi < 4; ++mi) {
#pragma unroll
        for (int r = 0; r < 4; ++r) {
            int row = m0 + wrow + mi * 16 + rbase + r;
            if (row < ne) {
                int slot = base + row;
                int tok = list[slot];
                float w = slot_w[slot];
                float* yrow = y + (size_t)tok * DDIM + n0 + wcol + cbase;
#pragma unroll
                for (int ni = 0; ni < 2; ++ni)
                    atomicAdd(yrow + ni * 16, w * acc[mi][ni][r]);
            }
        }
    }
}

extern "C" void kernel_launch(void* const* d_in, const int* in_sizes, int n_in,
                              void* d_out, int out_size, void* d_ws, size_t ws_size,
                              hipStream_t stream) {
    const float* x  = (const float*)d_in[0];
    const float* rw = (const float*)d_in[1];
    const float* wg = (const float*)d_in[2];
    const float* wu = (const float*)d_in[3];
    const float* wd = (const float*)d_in[4];
    float* y = (float*)d_out;

    char* ws = (char*)d_ws;
    int*   r_e    = (int*)  (ws + 0);           // 2T ints
    float* r_w    = (float*)(ws + 32768);       // 2T floats
    int*   offs   = (int*)  (ws + 65600);       // 9 (padded bases)
    int*   cnt    = (int*)  (ws + 65640);       // 8 real counts
    int*   list   = (int*)  (ws + 65792);       // MAXSLOT ints
    float* slot_w = (float*)(ws + 65792 + 4 * MAXSLOT);  // MAXSLOT floats
    bf16*  xb     = (bf16*) (ws + 1048576ull);      // 8 MB
    bf16*  wguT   = (bf16*) (ws + 16777216ull);     // 64 MB  [E][2H][D] interleaved g/u
    bf16*  wdT    = (bf16*) (ws + 83886080ull);     // 32 MB  [E][D][H]
    bf16*  hbuf   = (bf16*) (ws + 117440512ull);    // 37.75 MB [MAXSLOT][H]

    // all weight transposes + casts in one launch (12288 blocks)
    transpose_all_kernel<<<dim3(12288), 256, 0, stream>>>(wg, wu, wd, wguT, wdT);

    // routing (+ fused x cast + y zero) and padded binning
    router_cast_kernel<<<dim3(T_TOK / 4), 256, 0, stream>>>(x, rw, r_e, r_w, xb, y);
    binning_kernel<<<dim3(1), 512, 0, stream>>>(r_e, r_w, offs, cnt, list, slot_w);

    // expert GEMMs, compacted grids over padded slot-tiles
    gateup_kernel<<<dim3(2 * HDIM / 128, MAXSLOT / 128, 1), 512, 0, stream>>>(
        xb, wguT, offs, cnt, list, hbuf);
    down_kernel<<<dim3(DDIM / 128, MAXSLOT / 128, 1), 512, 0, stream>>>(
        hbuf, wdT, offs, cnt, list, slot_w, y);
}

// Round 17
// 276.715 us; speedup vs baseline: 1.0436x; 1.0048x over previous
//
#include <hip/hip_runtime.h>
#include <hip/hip_bf16.h>

#define T_TOK 4096
#define DDIM  1024
#define HDIM  2048
#define NEXP  8
#define MAXSLOT 9216   // 2T padded: each expert base 128-aligned

typedef __attribute__((ext_vector_type(4))) float f32x4;
typedef __attribute__((ext_vector_type(8))) short s16x8;
typedef __hip_bfloat16 bf16;

typedef const void __attribute__((address_space(1))) gvoid;
typedef void __attribute__((address_space(3))) svoid;

__device__ __forceinline__ void gload16(const void* g, void* l) {
    // async global->LDS, 16B/lane; LDS dest = wave-uniform base, HW adds lane*16
    __builtin_amdgcn_global_load_lds((gvoid*)g, (svoid*)l, 16, 0, 0);
}

// Conflict-free transpose tile swizzle (R16-proven): elem (r,c) at
// r*64 + 4*((c>>2) ^ sw(r)) + (c&3), sw(r) = ((r>>2) ^ ((r&3)<<2)) & 15.
__device__ __forceinline__ int sw_r(int r) { return ((r >> 2) ^ ((r & 3) << 2)) & 15; }

// ======== mega-prep: ALL weight transposes + router + x-cast + y-zero, ONE launch ======
// blocks [0,8192): wg/wu transpose -> wguT interleaved
// blocks [8192,12288): wd transpose -> wdT
// blocks [12288,13312): router (fp64 acc top-2 softmax) + x->bf16 cast + y-zero
__global__ void prep_kernel(const float* __restrict__ x, const float* __restrict__ rw,
                            const float* __restrict__ wg, const float* __restrict__ wu,
                            const float* __restrict__ wd,
                            bf16* __restrict__ wguT, bf16* __restrict__ wdT,
                            int* __restrict__ r_e, float* __restrict__ r_w,
                            bf16* __restrict__ xb, float* __restrict__ y) {
    int bid = blockIdx.x;
    int tid = threadIdx.x;

    if (bid >= 12288) {
        // ---- router + cast + y-zero ----
        int rb = bid - 12288;                  // [0,1024)
        {
            float4 z4 = {0.f, 0.f, 0.f, 0.f};
            size_t ybase = (size_t)rb * 4096 + tid * 4;
#pragma unroll
            for (int i = 0; i < 4; ++i)
                *reinterpret_cast<float4*>(y + ybase + (size_t)i * 1024) = z4;
        }
        int wave = tid >> 6, lane = tid & 63;
        int t = rb * 4 + wave;
        const float* xr = x + (size_t)t * DDIM;
        bf16* xbr = xb + (size_t)t * DDIM;
        double acc[NEXP];
#pragma unroll
        for (int e = 0; e < NEXP; ++e) acc[e] = 0.0;
#pragma unroll
        for (int c = 0; c < 4; ++c) {
            int d = c * 256 + lane * 4;
            float4 v = *reinterpret_cast<const float4*>(xr + d);
            union { ushort4 u; bf16 h[4]; } o;
            o.h[0] = __float2bfloat16(v.x);
            o.h[1] = __float2bfloat16(v.y);
            o.h[2] = __float2bfloat16(v.z);
            o.h[3] = __float2bfloat16(v.w);
            *reinterpret_cast<ushort4*>(xbr + d) = o.u;
            const float* rw0 = rw + (size_t)d * NEXP;
#pragma unroll
            for (int j = 0; j < 4; ++j) {
                float xv = (&v.x)[j];
                const float* rwr = rw0 + j * NEXP;
#pragma unroll
                for (int e = 0; e < NEXP; ++e) acc[e] += (double)xv * (double)rwr[e];
            }
        }
#pragma unroll
        for (int e = 0; e < NEXP; ++e) {
#pragma unroll
            for (int off = 32; off > 0; off >>= 1) acc[e] += __shfl_down(acc[e], off);
        }
        if (lane == 0) {
            int i0 = 0; double v0 = acc[0];
#pragma unroll
            for (int e = 1; e < NEXP; ++e) if (acc[e] > v0) { v0 = acc[e]; i0 = e; }
            int i1 = -1; double v1 = -1e300;
#pragma unroll
            for (int e = 0; e < NEXP; ++e) { if (e == i0) continue; if (acc[e] > v1) { v1 = acc[e]; i1 = e; } }
            float w0 = 1.0f / (1.0f + expf((float)(v1 - v0)));
            float w1 = 1.0f - w0;
            r_e[2*t]   = i0; r_e[2*t+1] = i1;
            r_w[2*t]   = w0; r_w[2*t+1] = w1;
        }
        return;
    }

    // ---- transpose paths ----
    __shared__ __align__(16) bf16 tile[64 * 64];
    const float* inp; bf16* outp; int C, OS, r0, c0;
    if (bid < 8192) {
        int z = bid >> 9;              // [0,16)
        int t = bid & 511;
        int which = z >> 3, e = z & 7;
        inp = (which ? wu : wg) + (size_t)e * DDIM * HDIM;   // [D][H]
        outp = wguT + (size_t)e * 2 * HDIM * DDIM + (size_t)which * DDIM;
        C = HDIM; OS = 2 * DDIM;
        r0 = (t >> 5) * 64;            // 16 r-tiles over D
        c0 = (t & 31) * 64;            // 32 c-tiles over H
    } else {
        int b2 = bid - 8192;
        int e = b2 >> 9;
        int t = b2 & 511;
        inp = wd + (size_t)e * HDIM * DDIM;                  // [H][D]
        outp = wdT + (size_t)e * DDIM * HDIM;
        C = DDIM; OS = HDIM;
        r0 = (t >> 4) * 64;            // 32 r-tiles over H
        c0 = (t & 15) * 64;            // 16 c-tiles over D
    }
#pragma unroll
    for (int i = 0; i < 4; ++i) {
        int idx = i * 256 + tid;
        int r = idx >> 4, c4 = (idx & 15) * 4;
        float4 v = *reinterpret_cast<const float4*>(inp + (size_t)(r0 + r) * C + c0 + c4);
        union { ushort4 u; bf16 h[4]; } o;
        o.h[0] = __float2bfloat16(v.x);
        o.h[1] = __float2bfloat16(v.y);
        o.h[2] = __float2bfloat16(v.z);
        o.h[3] = __float2bfloat16(v.w);
        *reinterpret_cast<ushort4*>(&tile[r * 64 + 4 * ((c4 >> 2) ^ sw_r(r))]) = o.u;
    }
    __syncthreads();
#pragma unroll
    for (int i = 0; i < 4; ++i) {
        int idx = i * 256 + tid;
        int c = idx >> 4, r4 = (idx & 15) * 4;
        int g = c >> 2, ce = c & 3;
        union { ushort4 u; bf16 h[4]; } w;
#pragma unroll
        for (int j = 0; j < 4; ++j) {
            int r = r4 + j;
            w.h[j] = tile[r * 64 + 4 * (g ^ sw_r(r)) + ce];
        }
        *reinterpret_cast<ushort4*>(outp + (size_t)(c0 + c) * OS + r0 + r4) = w.u;
    }
}

// ------- fused binning: count + 128-ALIGNED scan + fill, one block, 1024 thr -------
__global__ void binning_kernel(const int* __restrict__ r_e, const float* __restrict__ r_w,
                               int* __restrict__ offs, int* __restrict__ cnt,
                               int* __restrict__ list, float* __restrict__ slot_w) {
    __shared__ int scnt[NEXP], scur[NEXP], soff[NEXP + 1];
    int tid = threadIdx.x;
    if (tid < NEXP) { scnt[tid] = 0; scur[tid] = 0; }
    __syncthreads();
    for (int i = tid; i < 2 * T_TOK; i += 1024) atomicAdd(&scnt[r_e[i]], 1);
    __syncthreads();
    if (tid == 0) {
        int s = 0;
        for (int e = 0; e < NEXP; ++e) { soff[e] = s; s += (scnt[e] + 127) & ~127; }
        soff[NEXP] = s;
    }
    __syncthreads();
    if (tid < NEXP + 1) offs[tid] = soff[tid];
    if (tid < NEXP) cnt[tid] = scnt[tid];
    for (int i = tid; i < 2 * T_TOK; i += 1024) {
        int e = r_e[i];
        int pos = atomicAdd(&scur[e], 1);
        int slot = soff[e] + pos;
        list[slot] = i >> 1;
        slot_w[slot] = r_w[i];
    }
}

// expert lookup in padded slot space
__device__ __forceinline__ int find_expert(const int* offs, int slot0) {
    int e = 0;
#pragma unroll
    for (int i = 0; i < NEXP - 1; ++i) e += (offs[e + 1] <= slot0) ? 1 : 0;
    return e;
}

// ======== pass 1: gate+up as ONE GEMM over interleaved wguT [2H][D] ========
// R4/R15 geometry (best-measured): 128(M) x 128(N-in-2H), BK=64, 8 waves
// (2M x 4N, wave-out 64x32, acc[4][2]). 64 KB dbuf LDS. Counted vmcnt(4).
__global__ __launch_bounds__(512, 2)
void gateup_kernel(const bf16* __restrict__ xb, const bf16* __restrict__ wguT,
                   const int* __restrict__ offs, const int* __restrict__ cnt,
                   const int* __restrict__ list, bf16* __restrict__ hbuf) {
    int slot0 = blockIdx.y * 128;
    if (slot0 >= offs[NEXP]) return;
    int e = find_expert(offs, slot0);
    int base = offs[e];
    int ne = cnt[e];
    int m0 = slot0 - base;
    int n0 = blockIdx.x * 128;       // in 2H=4096 interleaved space

    __shared__ bf16 As[2][8192];     // 128 rows x 64 k (16 KB/buf)
    __shared__ bf16 Bs[2][8192];

    int tid = threadIdx.x, lane = tid & 63, wid = tid >> 6;   // 8 waves
    int sub = lane >> 3;                       // 0..7
    int koff = 8 * ((lane & 7) ^ sub);         // inverse-swizzled source chunk (row&7 == sub)

    const bf16* bbase = wguT + (size_t)e * (2 * HDIM) * DDIM + (size_t)n0 * DDIM;

    const bf16* aS[2]; const bf16* bS[2];
    int sdst[2];
#pragma unroll
    for (int j = 0; j < 2; ++j) {
        int q = wid + j * 8;                   // 0..15
        int row = q * 8 + sub;                 // [0,128)
        int r = m0 + row; if (r > ne - 1) r = ne - 1;   // clamp: read-only, never stored
        aS[j] = xb + (size_t)list[base + r] * DDIM + koff;
        bS[j] = bbase + (size_t)row * DDIM + koff;
        sdst[j] = q * 512;                     // wave-uniform elem offset
    }

    int rl = lane & 15, kq = 8 * (lane >> 4);
    int wrow = (wid >> 2) * 64;      // 2 M waves
    int wcol = (wid & 3) * 32;       // 4 N waves
    int xorv = (rl & 7) * 8;         // read-side swizzle

    f32x4 zero4 = {0.f, 0.f, 0.f, 0.f};
    f32x4 acc[4][2];
#pragma unroll
    for (int mi = 0; mi < 4; ++mi) { acc[mi][0] = zero4; acc[mi][1] = zero4; }

    const int nk = DDIM / 64;   // 16

#define GU_STAGE(tt, buf)                                     \
    {                                                         \
        int k0 = (tt) * 64;                                   \
        gload16(aS[0] + k0, &As[buf][sdst[0]]);               \
        gload16(aS[1] + k0, &As[buf][sdst[1]]);               \
        gload16(bS[0] + k0, &Bs[buf][sdst[0]]);               \
        gload16(bS[1] + k0, &Bs[buf][sdst[1]]);               \
    }

#define GU_COMPUTE(Ab, Bb)                                                        \
    _Pragma("unroll")                                                             \
    for (int kk = 0; kk < 2; ++kk) {                                              \
        int kos = (kk * 32 + kq) ^ xorv;                                          \
        s16x8 a[4], b[2];                                                         \
        _Pragma("unroll")                                                         \
        for (int mi = 0; mi < 4; ++mi)                                            \
            a[mi] = *reinterpret_cast<const s16x8*>(&(Ab)[(wrow + mi * 16 + rl) * 64 + kos]); \
        _Pragma("unroll")                                                         \
        for (int ni = 0; ni < 2; ++ni)                                            \
            b[ni] = *reinterpret_cast<const s16x8*>(&(Bb)[(wcol + ni * 16 + rl) * 64 + kos]); \
        __builtin_amdgcn_s_setprio(1);                                            \
        _Pragma("unroll")                                                         \
        for (int mi = 0; mi < 4; ++mi)                                            \
            _Pragma("unroll")                                                     \
            for (int ni = 0; ni < 2; ++ni)                                        \
                acc[mi][ni] = __builtin_amdgcn_mfma_f32_16x16x32_bf16(a[mi], b[ni], acc[mi][ni], 0, 0, 0); \
        __builtin_amdgcn_s_setprio(0);                                            \
    }

    GU_STAGE(0, 0);
    GU_STAGE(1, 1);

    for (int t = 0; t < nk; ++t) {
        if (t + 1 < nk) asm volatile("s_waitcnt vmcnt(4)" ::: "memory");   // tile t landed
        else            asm volatile("s_waitcnt vmcnt(0)" ::: "memory");
        __builtin_amdgcn_s_barrier();
        GU_COMPUTE(As[t & 1], Bs[t & 1]);
        __builtin_amdgcn_sched_barrier(0);
        __builtin_amdgcn_s_barrier();                 // buf[t&1] free
        if (t + 2 < nk) GU_STAGE(t + 2, t & 1);       // in flight: t+1(4) + t+2(4)
    }
#undef GU_COMPUTE
#undef GU_STAGE

    // epilogue: even col = gate, odd col = up; pair via shfl_xor(1), even lanes store.
    int rbase = (lane >> 4) * 4, cbase = lane & 15;
    bool evenlane = (lane & 1) == 0;
#pragma unroll
    for (int mi = 0; mi < 4; ++mi) {
#pragma unroll
        for (int ni = 0; ni < 2; ++ni) {
#pragma unroll
            for (int r = 0; r < 4; ++r) {
                float own = acc[mi][ni][r];
                float oth = __shfl_xor(own, 1);
                int row = m0 + wrow + mi * 16 + rbase + r;
                if (evenlane && row < ne) {
                    float g = own, u = oth;
                    float h = (g / (1.0f + expf(-g))) * u;
                    int hcol = (n0 + wcol + ni * 16 + cbase) >> 1;
                    hbuf[(size_t)(base + row) * HDIM + hcol] = __float2bfloat16(h);
                }
            }
        }
    }
}

// ======== pass 2: down GEMM, R15 structure at 128x128, BK=64 (32 iters) ========
__global__ __launch_bounds__(512, 2)
void down_kernel(const bf16* __restrict__ hbuf, const bf16* __restrict__ wdT,
                 const int* __restrict__ offs, const int* __restrict__ cnt,
                 const int* __restrict__ list, const float* __restrict__ slot_w,
                 float* __restrict__ y) {
    int slot0 = blockIdx.y * 128;
    if (slot0 >= offs[NEXP]) return;
    int e = find_expert(offs, slot0);
    int base = offs[e];
    int ne = cnt[e];
    int m0 = slot0 - base;
    int n0 = blockIdx.x * 128;   // d-tile

    __shared__ bf16 As[2][8192];
    __shared__ bf16 Bs[2][8192];

    int tid = threadIdx.x, lane = tid & 63, wid = tid >> 6;
    int sub = lane >> 3;
    int koff = 8 * ((lane & 7) ^ sub);

    const bf16* bbase = wdT + (size_t)e * DDIM * HDIM + (size_t)n0 * HDIM;

    const bf16* aS[2]; const bf16* bS[2];
    int sdst[2];
#pragma unroll
    for (int j = 0; j < 2; ++j) {
        int q = wid + j * 8;
        int row = q * 8 + sub;
        int r = m0 + row; if (r > ne - 1) r = ne - 1;
        aS[j] = hbuf + (size_t)(base + r) * HDIM + koff;
        bS[j] = bbase + (size_t)row * HDIM + koff;
        sdst[j] = q * 512;
    }

    int rl = lane & 15, kq = 8 * (lane >> 4);
    int wrow = (wid >> 2) * 64;
    int wcol = (wid & 3) * 32;
    int xorv = (rl & 7) * 8;

    f32x4 zero4 = {0.f, 0.f, 0.f, 0.f};
    f32x4 acc[4][2];
#pragma unroll
    for (int mi = 0; mi < 4; ++mi) { acc[mi][0] = zero4; acc[mi][1] = zero4; }

    const int nk = HDIM / 64;   // 32

#define DN_STAGE(tt, buf)                                     \
    {                                                         \
        int k0 = (tt) * 64;                                   \
        gload16(aS[0] + k0, &As[buf][sdst[0]]);               \
        gload16(aS[1] + k0, &As[buf][sdst[1]]);               \
        gload16(bS[0] + k0, &Bs[buf][sdst[0]]);               \
        gload16(bS[1] + k0, &Bs[buf][sdst[1]]);               \
    }

#define DN_COMPUTE(Ab, Bb)                                                        \
    _Pragma("unroll")                                                             \
    for (int kk = 0; kk < 2; ++kk) {                                              \
        int kos = (kk * 32 + kq) ^ xorv;                                          \
        s16x8 a[4], b[2];                                                         \
        _Pragma("unroll")                                                         \
        for (int mi = 0; mi < 4; ++mi)                                            \
            a[mi] = *reinterpret_cast<const s16x8*>(&(Ab)[(wrow + mi * 16 + rl) * 64 + kos]); \
        _Pragma("unroll")                                                         \
        for (int ni = 0; ni < 2; ++ni)                                            \
            b[ni] = *reinterpret_cast<const s16x8*>(&(Bb)[(wcol + ni * 16 + rl) * 64 + kos]); \
        __builtin_amdgcn_s_setprio(1);                                            \
        _Pragma("unroll")                                                         \
        for (int mi = 0; mi < 4; ++mi)                                            \
            _Pragma("unroll")                                                     \
            for (int ni = 0; ni < 2; ++ni)                                        \
                acc[mi][ni] = __builtin_amdgcn_mfma_f32_16x16x32_bf16(a[mi], b[ni], acc[mi][ni], 0, 0, 0); \
        __builtin_amdgcn_s_setprio(0);                                            \
    }

    DN_STAGE(0, 0);
    DN_STAGE(1, 1);

    for (int t = 0; t < nk; ++t) {
        if (t + 1 < nk) asm volatile("s_waitcnt vmcnt(4)" ::: "memory");
        else            asm volatile("s_waitcnt vmcnt(0)" ::: "memory");
        __builtin_amdgcn_s_barrier();
        DN_COMPUTE(As[t & 1], Bs[t & 1]);
        __builtin_amdgcn_sched_barrier(0);
        __builtin_amdgcn_s_barrier();
        if (t + 2 < nk) DN_STAGE(t + 2, t & 1);
    }
#undef DN_COMPUTE
#undef DN_STAGE

    // epilogue: y[tok][col] += w * acc  (2 adds per element, commutative -> deterministic)
    int rbase = (lane >> 4) * 4, cbase = lane & 15;
#pragma unroll
    for (int mi = 0; mi < 4; ++mi) {
#pragma unroll
        for (int r = 0; r < 4; ++r) {
            int row = m0 + wrow + mi * 16 + rbase + r;
            if (row < ne) {
                int slot = base + row;
                int tok = list[slot];
                float w = slot_w[slot];
                float* yrow = y + (size_t)tok * DDIM + n0 + wcol + cbase;
#pragma unroll
                for (int ni = 0; ni < 2; ++ni)
                    atomicAdd(yrow + ni * 16, w * acc[mi][ni][r]);
            }
        }
    }
}

extern "C" void kernel_launch(void* const* d_in, const int* in_sizes, int n_in,
                              void* d_out, int out_size, void* d_ws, size_t ws_size,
                              hipStream_t stream) {
    const float* x  = (const float*)d_in[0];
    const float* rw = (const float*)d_in[1];
    const float* wg = (const float*)d_in[2];
    const float* wu = (const float*)d_in[3];
    const float* wd = (const float*)d_in[4];
    float* y = (float*)d_out;

    char* ws = (char*)d_ws;
    int*   r_e    = (int*)  (ws + 0);           // 2T ints
    float* r_w    = (float*)(ws + 32768);       // 2T floats
    int*   offs   = (int*)  (ws + 65600);       // 9 (padded bases)
    int*   cnt    = (int*)  (ws + 65640);       // 8 real counts
    int*   list   = (int*)  (ws + 65792);       // MAXSLOT ints
    float* slot_w = (float*)(ws + 65792 + 4 * MAXSLOT);  // MAXSLOT floats
    bf16*  xb     = (bf16*) (ws + 1048576ull);      // 8 MB
    bf16*  wguT   = (bf16*) (ws + 16777216ull);     // 64 MB  [E][2H][D] interleaved g/u
    bf16*  wdT    = (bf16*) (ws + 83886080ull);     // 32 MB  [E][D][H]
    bf16*  hbuf   = (bf16*) (ws + 117440512ull);    // 37.75 MB [MAXSLOT][H]

    // ONE prep launch: all transposes + router + x-cast + y-zero (13312 blocks)
    prep_kernel<<<dim3(13312), 256, 0, stream>>>(x, rw, wg, wu, wd, wguT, wdT,
                                                 r_e, r_w, xb, y);
    binning_kernel<<<dim3(1), 1024, 0, stream>>>(r_e, r_w, offs, cnt, list, slot_w);

    // expert GEMMs, compacted grids over padded slot-tiles
    gateup_kernel<<<dim3(2 * HDIM / 128, MAXSLOT / 128, 1), 512, 0, stream>>>(
        xb, wguT, offs, cnt, list, hbuf);
    down_kernel<<<dim3(DDIM / 128, MAXSLOT / 128, 1), 512, 0, stream>>>(
        hbuf, wdT, offs, cnt, list, slot_w, y);
}